// Round 3
// baseline (136.105 us; speedup 1.0000x reference)
//
#include <hip/hip_runtime.h>

#define B_DIM 4096
#define I_DIM 1024
#define O_DIM 1024
#define ON_DIM 4096      // O * N fan-in columns
#define TILE_HALFS 4096  // one 128(m) x 32(k) fp16 tile image = 8 KB
                         // image order: [kb8(4)][m(128)][j(8)] halfs

typedef _Float16 half8  __attribute__((ext_vector_type(8)));
typedef _Float16 half4_t __attribute__((ext_vector_type(4)));
typedef float    floatx4 __attribute__((ext_vector_type(4)));

// ---------------------------------------------------------------------------
// Kernel A: per-row softmax stats (max, 1/sum) — one wave per row.
// ---------------------------------------------------------------------------
__global__ __launch_bounds__(256)
void ltn_stats(const float* __restrict__ logits, float2* __restrict__ stats) {
  const int t = threadIdx.x, lane = t & 63, wv = t >> 6;
  const int row = blockIdx.x * 4 + wv;
  const float4* src = (const float4*)(logits + (size_t)row * I_DIM);
  float4 v[4];
#pragma unroll
  for (int j = 0; j < 4; j++) v[j] = src[j * 64 + lane];
  float m = -1e30f;
#pragma unroll
  for (int j = 0; j < 4; j++)
    m = fmaxf(m, fmaxf(fmaxf(v[j].x, v[j].y), fmaxf(v[j].z, v[j].w)));
#pragma unroll
  for (int off = 1; off < 64; off <<= 1) m = fmaxf(m, __shfl_xor(m, off));
  float s = 0.0f;
#pragma unroll
  for (int j = 0; j < 4; j++) {
    s += __expf(v[j].x - m) + __expf(v[j].y - m)
       + __expf(v[j].z - m) + __expf(v[j].w - m);
  }
#pragma unroll
  for (int off = 1; off < 64; off <<= 1) s += __shfl_xor(s, off);
  if (lane == 0) stats[row] = make_float2(m, 1.0f / s);
}

// ---------------------------------------------------------------------------
// Kernel B: fully-coalesced tile writer.
//  blocks [0,1024):    wt tile (nb,kb): softmax-normalize 128x32 logits block
//  blocks [1024,2048): xt tile (mb,kt): fp32->fp16 convert 128x32 x block
// ---------------------------------------------------------------------------
__global__ __launch_bounds__(256)
void ltn_tile(const float* __restrict__ logits, const float* __restrict__ x,
              const float2* __restrict__ stats,
              _Float16* __restrict__ wt, _Float16* __restrict__ xt) {
  const int t  = threadIdx.x;
  const int nn = t >> 1;        // row within 128-tile
  const int hf = t & 1;         // which 16-k half of the 32-k tile
  if (blockIdx.x < 1024) {
    const int nb = blockIdx.x >> 5, kb = blockIdx.x & 31;
    const int row = nb * 128 + nn;
    const float2 st = stats[row];
    const float4* src = (const float4*)(logits + (size_t)row * I_DIM + kb * 32 + hf * 16);
    const float4 a = src[0], b = src[1], c = src[2], d = src[3];
    half8 h0, h1;
    h0[0] = (_Float16)(__expf(a.x - st.x) * st.y);
    h0[1] = (_Float16)(__expf(a.y - st.x) * st.y);
    h0[2] = (_Float16)(__expf(a.z - st.x) * st.y);
    h0[3] = (_Float16)(__expf(a.w - st.x) * st.y);
    h0[4] = (_Float16)(__expf(b.x - st.x) * st.y);
    h0[5] = (_Float16)(__expf(b.y - st.x) * st.y);
    h0[6] = (_Float16)(__expf(b.z - st.x) * st.y);
    h0[7] = (_Float16)(__expf(b.w - st.x) * st.y);
    h1[0] = (_Float16)(__expf(c.x - st.x) * st.y);
    h1[1] = (_Float16)(__expf(c.y - st.x) * st.y);
    h1[2] = (_Float16)(__expf(c.z - st.x) * st.y);
    h1[3] = (_Float16)(__expf(c.w - st.x) * st.y);
    h1[4] = (_Float16)(__expf(d.x - st.x) * st.y);
    h1[5] = (_Float16)(__expf(d.y - st.x) * st.y);
    h1[6] = (_Float16)(__expf(d.z - st.x) * st.y);
    h1[7] = (_Float16)(__expf(d.w - st.x) * st.y);
    _Float16* base = wt + ((size_t)nb * 32 + kb) * TILE_HALFS + (hf * 2) * 1024 + nn * 8;
    *(half8*)base = h0;
    *(half8*)(base + 1024) = h1;
  } else {
    const int bid = blockIdx.x - 1024;
    const int mb = bid >> 5, kt = bid & 31;
    const int row = mb * 128 + nn;
    const float4* src = (const float4*)(x + (size_t)row * I_DIM + kt * 32 + hf * 16);
    const float4 a = src[0], b = src[1], c = src[2], d = src[3];
    half8 h0, h1;
    h0[0] = (_Float16)a.x; h0[1] = (_Float16)a.y; h0[2] = (_Float16)a.z; h0[3] = (_Float16)a.w;
    h0[4] = (_Float16)b.x; h0[5] = (_Float16)b.y; h0[6] = (_Float16)b.z; h0[7] = (_Float16)b.w;
    h1[0] = (_Float16)c.x; h1[1] = (_Float16)c.y; h1[2] = (_Float16)c.z; h1[3] = (_Float16)c.w;
    h1[4] = (_Float16)d.x; h1[5] = (_Float16)d.y; h1[6] = (_Float16)d.z; h1[7] = (_Float16)d.w;
    _Float16* base = xt + ((size_t)mb * 32 + kt) * TILE_HALFS + (hf * 2) * 1024 + nn * 8;
    *(half8*)base = h0;
    *(half8*)(base + 1024) = h1;
  }
}

// ---------------------------------------------------------------------------
// GEMM + sigmoid + 16-corner LUT. 256x256 block tile (8 waves, 4x2), BK=32.
// R2/R3: port of the PROVEN m201 8-phase schedule (2 phases per BK=32 k-tile):
//   phase = { ds_read frag subtile | stage 2 GLL |
//             barrier | lgkmcnt(0) | setprio(1) 16xMFMA setprio(0) | barrier }
// 4-buffer LDS (128 KB), stage 3 k-tiles ahead, counted vmcnt(8) ONCE per
// k-tile (drains the stage group for k-tile kt+1, issued at kt-2; keeps the
// newest 8 GLLs in flight across barriers). Tail: vmcnt 8 -> 4 -> 0.
// Rationale: R0/R1 both sat at ~4100 cyc/K-step (MFMA floor 1030) with
// identical perf despite different vmcnt discipline -> the stall is ds_read
// latency exposure in a coarse lockstep phase, which only the fine-grained
// interleave removes (m196->m198: +28-41%, independent of LDS swizzle; our
// packed tile image already gives 0 bank conflicts).
// ---------------------------------------------------------------------------
__global__ __launch_bounds__(512, 2)
void ltn_gemm_lut(const _Float16* __restrict__ xt,   // tiles [32*32][TILE_HALFS]
                  const _Float16* __restrict__ wt,
                  const float* __restrict__ lut,     // [O][16]
                  float* __restrict__ out) {         // [B][O]
  // 4 buffers x (A: 8192 halfs | B: 8192 halfs) = 128 KB
  __shared__ _Float16 sm[4 * 16384];

  const int tid  = threadIdx.x;
  const int lane = tid & 63;
  const int wv   = tid >> 6;     // 0..7
  const int wr   = wv >> 1;      // row-wave 0..3  (64 rows each)
  const int wc   = wv & 1;       // col-wave 0..1  (128 cols each)

  // XCD-chunked swizzle (kept from R1: FETCH_SIZE -33%).
  const int id  = blockIdx.x;    // 0..255
  const int xcd = id & 7;
  const int li  = id >> 3;       // 0..31
  const int mb  = (xcd & 3) * 4 + (li & 3);
  const int nb  = (xcd >> 2) * 8 + (li >> 2);

  const int fm = lane & 15;
  const int kq = lane >> 4;

  const size_t baseA = (size_t)(mb * 2) * 32 * TILE_HALFS;
  const size_t baseB = (size_t)(nb * 2) * 32 * TILE_HALFS;

  floatx4 acc[4][8];
#pragma unroll
  for (int i = 0; i < 4; i++)
#pragma unroll
    for (int j = 0; j < 8; j++) acc[i][j] = (floatx4)0.0f;

  // 32 chunks of 1KB per k-tile (16 A + 16 B); wave wv owns chunks wv*4+s.
  // stage2 issues the pair s = sLo, sLo+1 (2 GLLs per wave per phase).
  auto stage2 = [&](int bufOff /*halfs*/, int kt, int sLo) {
#pragma unroll
    for (int s = sLo; s < sLo + 2; s++) {
      const int c   = wv * 4 + s;        // 0..31, wave-uniform split
      const int cc  = c & 15;            // chunk within matrix
      const int tl  = cc >> 3;           // which 128-row tile (0/1)
      const int sub = cc & 7;            // 1KB sub-chunk
      const _Float16* g;
      int dst;
      if (c < 16) {
        g = xt + baseA + (size_t)(tl * 32 + kt) * TILE_HALFS + sub * 512 + lane * 8;
        dst = bufOff + cc * 512;
      } else {
        g = wt + baseB + (size_t)(tl * 32 + kt) * TILE_HALFS + sub * 512 + lane * 8;
        dst = bufOff + 8192 + cc * 512;
      }
      __builtin_amdgcn_global_load_lds(
          (const __attribute__((address_space(1))) void*)g,
          (__attribute__((address_space(3))) void*)(sm + dst), 16, 0, 0);
    }
  };

  // Prologue: stage k-tiles 0,1,2 (12 GLLs per wave); drain k-tile 0's 4
  // (keep 8 newest in flight) and sync before first reads.
  stage2(0,     0, 0); stage2(0,     0, 2);
  stage2(16384, 1, 0); stage2(16384, 1, 2);
  stage2(32768, 2, 0); stage2(32768, 2, 2);
  asm volatile("s_waitcnt vmcnt(8)" ::: "memory");
  __builtin_amdgcn_s_barrier();

  half8 af[4], bf[8];

#pragma unroll 1
  for (int kt = 0; kt < 32; kt++) {
    const int rb = (kt & 3) * 16384;           // read buffer
    const int sb = ((kt + 3) & 3) * 16384;     // stage buffer (k-tile kt+3)
    const bool doStage = (kt + 3 < 32);

    // ---------------- phase 0: af[0..3], bf[0..3] -> MFMA nt 0..3 ----------
#pragma unroll
    for (int f = 0; f < 4; f++)
      af[f] = *(const half8*)&sm[rb + (wr >> 1) * 4096 + kq * 1024
                                 + ((wr & 1) * 64 + f * 16 + fm) * 8];
#pragma unroll
    for (int g = 0; g < 4; g++)
      bf[g] = *(const half8*)&sm[rb + 8192 + wc * 4096 + kq * 1024
                                 + (g * 16 + fm) * 8];
    if (doStage) stage2(sb, kt + 3, 0);
    __builtin_amdgcn_sched_barrier(0);
    __builtin_amdgcn_s_barrier();
    asm volatile("s_waitcnt lgkmcnt(0)" ::: "memory");
    __builtin_amdgcn_sched_barrier(0);
    __builtin_amdgcn_s_setprio(1);
#pragma unroll
    for (int mt = 0; mt < 4; mt++)
#pragma unroll
      for (int nt = 0; nt < 4; nt++)
        acc[mt][nt] = __builtin_amdgcn_mfma_f32_16x16x32_f16(
            af[mt], bf[nt], acc[mt][nt], 0, 0, 0);
    __builtin_amdgcn_s_setprio(0);
    __builtin_amdgcn_s_barrier();

    // ---------------- phase 1: bf[4..7] -> MFMA nt 4..7 --------------------
#pragma unroll
    for (int g = 4; g < 8; g++)
      bf[g] = *(const half8*)&sm[rb + 8192 + wc * 4096 + kq * 1024
                                 + (g * 16 + fm) * 8];
    if (doStage) stage2(sb, kt + 3, 2);
    // Counted vmcnt (once per k-tile): buffer for k-tile kt+1 was staged at
    // k-tile kt-2; drain that group, keep the 8 issued at kt-1 and kt.
    if (kt < 29)       asm volatile("s_waitcnt vmcnt(8)" ::: "memory");
    else if (kt == 29) asm volatile("s_waitcnt vmcnt(4)" ::: "memory");
    else if (kt == 30) asm volatile("s_waitcnt vmcnt(0)" ::: "memory");
    __builtin_amdgcn_sched_barrier(0);
    __builtin_amdgcn_s_barrier();
    asm volatile("s_waitcnt lgkmcnt(0)" ::: "memory");
    __builtin_amdgcn_sched_barrier(0);
    __builtin_amdgcn_s_setprio(1);
#pragma unroll
    for (int mt = 0; mt < 4; mt++)
#pragma unroll
      for (int nt = 4; nt < 8; nt++)
        acc[mt][nt] = __builtin_amdgcn_mfma_f32_16x16x32_f16(
            af[mt], bf[nt], acc[mt][nt], 0, 0, 0);
    __builtin_amdgcn_s_setprio(0);
    __builtin_amdgcn_s_barrier();
  }

  // ---- fused epilogue: sigmoid -> gather 4 fan-in values -> LUT contraction
  // C/D layout: col = lane&15, row = (lane>>4)*4 + reg. The 4 n-values of one
  // o live in 4 consecutive lanes.
#pragma unroll
  for (int nt = 0; nt < 8; nt++) {
    const int o = (nb * 256 + wc * 128 + nt * 16 + fm) >> 2;
    const float4* lt4 = (const float4*)(lut + (size_t)o * 16);
    const float4 L0 = lt4[0], L1 = lt4[1], L2 = lt4[2], L3 = lt4[3];
#pragma unroll
    for (int mt = 0; mt < 4; mt++) {
#pragma unroll
      for (int r = 0; r < 4; r++) {
        const float v  = acc[mt][nt][r];
        const float sv = 1.0f / (1.0f + __expf(-v));
        const float s1 = __shfl_down(sv, 1);
        const float s2 = __shfl_down(sv, 2);
        const float s3 = __shfl_down(sv, 3);
        if ((lane & 3) == 0) {
          const float s0 = sv;
          const float a0 = L0.x + (L2.x - L0.x) * s3;
          const float a1 = L0.y + (L2.y - L0.y) * s3;
          const float a2 = L0.z + (L2.z - L0.z) * s3;
          const float a3 = L0.w + (L2.w - L0.w) * s3;
          const float a4 = L1.x + (L3.x - L1.x) * s3;
          const float a5 = L1.y + (L3.y - L1.y) * s3;
          const float a6 = L1.z + (L3.z - L1.z) * s3;
          const float a7 = L1.w + (L3.w - L1.w) * s3;
          const float b0 = a0 + (a4 - a0) * s2;
          const float b1 = a1 + (a5 - a1) * s2;
          const float b2 = a2 + (a6 - a2) * s2;
          const float b3 = a3 + (a7 - a3) * s2;
          const float c0 = b0 + (b2 - b0) * s1;
          const float c1 = b1 + (b3 - b1) * s1;
          const float res = c0 + (c1 - c0) * s0;
          const int row = mb * 256 + wr * 64 + mt * 16 + (lane >> 4) * 4 + r;
          out[(size_t)row * O_DIM + o] = res;
        }
      }
    }
  }
}

// ---------------------------------------------------------------------------
extern "C" void kernel_launch(void* const* d_in, const int* in_sizes, int n_in,
                              void* d_out, int out_size, void* d_ws, size_t ws_size,
                              hipStream_t stream) {
  const float* x      = (const float*)d_in[0];  // (B, I)
  const float* logits = (const float*)d_in[1];  // (O, N, I)
  const float* lut    = (const float*)d_in[2];  // (O, 16)
  float* out          = (float*)d_out;          // (B, O)

  _Float16* wt = (_Float16*)d_ws;                                  // 8 MB tiled
  _Float16* xt = (_Float16*)d_ws + (size_t)ON_DIM * I_DIM;         // 8 MB tiled
  // stats scratch parked in d_out (32 KB); GEMM fully overwrites d_out later.
  float2* stats = (float2*)d_out;

  ltn_stats<<<1024, 256, 0, stream>>>(logits, stats);
  ltn_tile<<<2048, 256, 0, stream>>>(logits, x, stats, wt, xt);
  dim3 grid(256);
  ltn_gemm_lut<<<grid, 512, 0, stream>>>(xt, wt, lut, out);
}

// Round 4
// 132.814 us; speedup vs baseline: 1.0248x; 1.0248x over previous
//
#include <hip/hip_runtime.h>

#define B_DIM 4096
#define I_DIM 1024
#define O_DIM 1024
#define ON_DIM 4096      // O * N fan-in columns
#define TILE_HALFS 4096  // one 128(m) x 32(k) fp16 tile image = 8 KB
                         // image order: [kb8(4)][m(128)][j(8)] halfs

typedef _Float16 half8  __attribute__((ext_vector_type(8)));
typedef _Float16 half4_t __attribute__((ext_vector_type(4)));
typedef float    floatx4 __attribute__((ext_vector_type(4)));

// ---------------------------------------------------------------------------
// Kernel A: per-row softmax stats (max, 1/sum) — one wave per row.
// ---------------------------------------------------------------------------
__global__ __launch_bounds__(256)
void ltn_stats(const float* __restrict__ logits, float2* __restrict__ stats) {
  const int t = threadIdx.x, lane = t & 63, wv = t >> 6;
  const int row = blockIdx.x * 4 + wv;
  const float4* src = (const float4*)(logits + (size_t)row * I_DIM);
  float4 v[4];
#pragma unroll
  for (int j = 0; j < 4; j++) v[j] = src[j * 64 + lane];
  float m = -1e30f;
#pragma unroll
  for (int j = 0; j < 4; j++)
    m = fmaxf(m, fmaxf(fmaxf(v[j].x, v[j].y), fmaxf(v[j].z, v[j].w)));
#pragma unroll
  for (int off = 1; off < 64; off <<= 1) m = fmaxf(m, __shfl_xor(m, off));
  float s = 0.0f;
#pragma unroll
  for (int j = 0; j < 4; j++) {
    s += __expf(v[j].x - m) + __expf(v[j].y - m)
       + __expf(v[j].z - m) + __expf(v[j].w - m);
  }
#pragma unroll
  for (int off = 1; off < 64; off <<= 1) s += __shfl_xor(s, off);
  if (lane == 0) stats[row] = make_float2(m, 1.0f / s);
}

// ---------------------------------------------------------------------------
// Kernel B: fully-coalesced tile writer.
//  blocks [0,1024):    wt tile (nb,kb): softmax-normalize 128x32 logits block
//  blocks [1024,2048): xt tile (mb,kt): fp32->fp16 convert 128x32 x block
// ---------------------------------------------------------------------------
__global__ __launch_bounds__(256)
void ltn_tile(const float* __restrict__ logits, const float* __restrict__ x,
              const float2* __restrict__ stats,
              _Float16* __restrict__ wt, _Float16* __restrict__ xt) {
  const int t  = threadIdx.x;
  const int nn = t >> 1;        // row within 128-tile
  const int hf = t & 1;         // which 16-k half of the 32-k tile
  if (blockIdx.x < 1024) {
    const int nb = blockIdx.x >> 5, kb = blockIdx.x & 31;
    const int row = nb * 128 + nn;
    const float2 st = stats[row];
    const float4* src = (const float4*)(logits + (size_t)row * I_DIM + kb * 32 + hf * 16);
    const float4 a = src[0], b = src[1], c = src[2], d = src[3];
    half8 h0, h1;
    h0[0] = (_Float16)(__expf(a.x - st.x) * st.y);
    h0[1] = (_Float16)(__expf(a.y - st.x) * st.y);
    h0[2] = (_Float16)(__expf(a.z - st.x) * st.y);
    h0[3] = (_Float16)(__expf(a.w - st.x) * st.y);
    h0[4] = (_Float16)(__expf(b.x - st.x) * st.y);
    h0[5] = (_Float16)(__expf(b.y - st.x) * st.y);
    h0[6] = (_Float16)(__expf(b.z - st.x) * st.y);
    h0[7] = (_Float16)(__expf(b.w - st.x) * st.y);
    h1[0] = (_Float16)(__expf(c.x - st.x) * st.y);
    h1[1] = (_Float16)(__expf(c.y - st.x) * st.y);
    h1[2] = (_Float16)(__expf(c.z - st.x) * st.y);
    h1[3] = (_Float16)(__expf(c.w - st.x) * st.y);
    h1[4] = (_Float16)(__expf(d.x - st.x) * st.y);
    h1[5] = (_Float16)(__expf(d.y - st.x) * st.y);
    h1[6] = (_Float16)(__expf(d.z - st.x) * st.y);
    h1[7] = (_Float16)(__expf(d.w - st.x) * st.y);
    _Float16* base = wt + ((size_t)nb * 32 + kb) * TILE_HALFS + (hf * 2) * 1024 + nn * 8;
    *(half8*)base = h0;
    *(half8*)(base + 1024) = h1;
  } else {
    const int bid = blockIdx.x - 1024;
    const int mb = bid >> 5, kt = bid & 31;
    const int row = mb * 128 + nn;
    const float4* src = (const float4*)(x + (size_t)row * I_DIM + kt * 32 + hf * 16);
    const float4 a = src[0], b = src[1], c = src[2], d = src[3];
    half8 h0, h1;
    h0[0] = (_Float16)a.x; h0[1] = (_Float16)a.y; h0[2] = (_Float16)a.z; h0[3] = (_Float16)a.w;
    h0[4] = (_Float16)b.x; h0[5] = (_Float16)b.y; h0[6] = (_Float16)b.z; h0[7] = (_Float16)b.w;
    h1[0] = (_Float16)c.x; h1[1] = (_Float16)c.y; h1[2] = (_Float16)c.z; h1[3] = (_Float16)c.w;
    h1[4] = (_Float16)d.x; h1[5] = (_Float16)d.y; h1[6] = (_Float16)d.z; h1[7] = (_Float16)d.w;
    _Float16* base = xt + ((size_t)mb * 32 + kt) * TILE_HALFS + (hf * 2) * 1024 + nn * 8;
    *(half8*)base = h0;
    *(half8*)(base + 1024) = h1;
  }
}

// ---------------------------------------------------------------------------
// GEMM + sigmoid + 16-corner LUT.  R4 RESTRUCTURE: m97/m103-proven geometry.
// Post-mortem R0-R3: three schedules at 256^2/1-block-per-CU all pinned at
// 610-630 TF. R3's strict lockstep matched a serial model exactly:
// per phase [8 waves x 8 ds_read_b128 ~ 768 cyc LDS-pipe drain] then
// [512 cyc MFMA] with NO overlap — one resident block has nothing to run
// during either phase. Fix = multi-block overlap (m114 mechanism; m103:
// 912 TF ref-checked at this exact geometry):
//   128x128 tile, 4 waves (2x2, 64x64 each), BK=32, double-buffered 32KB LDS,
//   grid 32x32 = 1024 blocks = 4 blocks/CU, plain __syncthreads loop,
//   global_load_lds width 16, XCD-chunked swizzle (8mb x 16nb per XCD).
// Block A's MFMA phase now co-schedules against blocks B/C/D's LDS-drain and
// staging phases on the same CU.
// ---------------------------------------------------------------------------
__global__ __launch_bounds__(256, 4)
void ltn_gemm_lut(const _Float16* __restrict__ xt,   // tiles [32*32][TILE_HALFS]
                  const _Float16* __restrict__ wt,
                  const float* __restrict__ lut,     // [O][16]
                  float* __restrict__ out) {         // [B][O]
  __shared__ _Float16 As[2][4][128][8];   // [buf][kb8][m][j] = tile image, 2x8KB
  __shared__ _Float16 Bs[2][4][128][8];

  const int tid  = threadIdx.x;
  const int lane = tid & 63;
  const int wv   = tid >> 6;     // 0..3
  const int wr   = wv >> 1;      // row-wave 0..1  (64 rows each)
  const int wc   = wv & 1;       // col-wave 0..1  (64 cols each)

  // XCD-chunked swizzle: 1024 blocks, id&7 -> XCD; each XCD owns an
  // 8(mb) x 16(nb) chunk. Bijective.
  const int id  = blockIdx.x;    // 0..1023
  const int xcd = id & 7;
  const int li  = id >> 3;       // 0..127
  const int mb  = (xcd & 3) * 8 + (li & 7);     // 0..31
  const int nb  = (xcd >> 2) * 16 + (li >> 3);  // 0..31

  const int fm = lane & 15;
  const int kq = lane >> 4;

  const size_t baseA = (size_t)mb * 32 * TILE_HALFS;
  const size_t baseB = (size_t)nb * 32 * TILE_HALFS;

  floatx4 acc[4][4];
#pragma unroll
  for (int i = 0; i < 4; i++)
#pragma unroll
    for (int j = 0; j < 4; j++) acc[i][j] = (floatx4)0.0f;

  // 16 chunks of 1KB per k-tile (8 A + 8 B); wave wv stages chunks wv*4+s.
  auto stage = [&](int buf, int kt) {
#pragma unroll
    for (int s = 0; s < 4; s++) {
      const int c = wv * 4 + s;          // 0..15, wave-uniform
      const _Float16* g;
      char* l;
      if (c < 8) {
        g = xt + baseA + (size_t)kt * TILE_HALFS + c * 512 + lane * 8;
        l = (char*)&As[buf][0][0][0] + c * 1024;
      } else {
        g = wt + baseB + (size_t)kt * TILE_HALFS + (c - 8) * 512 + lane * 8;
        l = (char*)&Bs[buf][0][0][0] + (c - 8) * 1024;
      }
      __builtin_amdgcn_global_load_lds(
          (const __attribute__((address_space(1))) void*)g,
          (__attribute__((address_space(3))) void*)l, 16, 0, 0);
    }
  };

  auto compute = [&](int buf) {
    half8 af[4], bf[4];
#pragma unroll
    for (int f = 0; f < 4; f++)
      af[f] = *(const half8*)&As[buf][kq][wr * 64 + f * 16 + fm][0];
#pragma unroll
    for (int g = 0; g < 4; g++)
      bf[g] = *(const half8*)&Bs[buf][kq][wc * 64 + g * 16 + fm][0];
#pragma unroll
    for (int mt = 0; mt < 4; mt++)
#pragma unroll
      for (int nt = 0; nt < 4; nt++)
        acc[mt][nt] = __builtin_amdgcn_mfma_f32_16x16x32_f16(
            af[mt], bf[nt], acc[mt][nt], 0, 0, 0);
  };

  stage(0, 0);
  int buf = 0;
#pragma unroll 1
  for (int kt = 0; kt < 32; kt++) {
    __syncthreads();
    if (kt + 1 < 32) stage(buf ^ 1, kt + 1);
    compute(buf);
    buf ^= 1;
  }

  // ---- fused epilogue: sigmoid -> gather 4 fan-in values -> LUT contraction
  // C/D layout: col = lane&15, row = (lane>>4)*4 + reg. The 4 n-values of one
  // o live in 4 consecutive lanes.
#pragma unroll
  for (int nt = 0; nt < 4; nt++) {
    const int o = (nb * 128 + wc * 64 + nt * 16 + fm) >> 2;
    const float4* lt4 = (const float4*)(lut + (size_t)o * 16);
    const float4 L0 = lt4[0], L1 = lt4[1], L2 = lt4[2], L3 = lt4[3];
#pragma unroll
    for (int mt = 0; mt < 4; mt++) {
#pragma unroll
      for (int r = 0; r < 4; r++) {
        const float v  = acc[mt][nt][r];
        const float sv = 1.0f / (1.0f + __expf(-v));
        const float s1 = __shfl_down(sv, 1);
        const float s2 = __shfl_down(sv, 2);
        const float s3 = __shfl_down(sv, 3);
        if ((lane & 3) == 0) {
          const float s0 = sv;
          const float a0 = L0.x + (L2.x - L0.x) * s3;
          const float a1 = L0.y + (L2.y - L0.y) * s3;
          const float a2 = L0.z + (L2.z - L0.z) * s3;
          const float a3 = L0.w + (L2.w - L0.w) * s3;
          const float a4 = L1.x + (L3.x - L1.x) * s3;
          const float a5 = L1.y + (L3.y - L1.y) * s3;
          const float a6 = L1.z + (L3.z - L1.z) * s3;
          const float a7 = L1.w + (L3.w - L1.w) * s3;
          const float b0 = a0 + (a4 - a0) * s2;
          const float b1 = a1 + (a5 - a1) * s2;
          const float b2 = a2 + (a6 - a2) * s2;
          const float b3 = a3 + (a7 - a3) * s2;
          const float c0 = b0 + (b2 - b0) * s1;
          const float c1 = b1 + (b3 - b1) * s1;
          const float res = c0 + (c1 - c0) * s0;
          const int row = mb * 128 + wr * 64 + mt * 16 + (lane >> 4) * 4 + r;
          out[(size_t)row * O_DIM + o] = res;
        }
      }
    }
  }
}

// ---------------------------------------------------------------------------
extern "C" void kernel_launch(void* const* d_in, const int* in_sizes, int n_in,
                              void* d_out, int out_size, void* d_ws, size_t ws_size,
                              hipStream_t stream) {
  const float* x      = (const float*)d_in[0];  // (B, I)
  const float* logits = (const float*)d_in[1];  // (O, N, I)
  const float* lut    = (const float*)d_in[2];  // (O, 16)
  float* out          = (float*)d_out;          // (B, O)

  _Float16* wt = (_Float16*)d_ws;                                  // 8 MB tiled
  _Float16* xt = (_Float16*)d_ws + (size_t)ON_DIM * I_DIM;         // 8 MB tiled
  // stats scratch parked in d_out (32 KB); GEMM fully overwrites d_out later.
  float2* stats = (float2*)d_out;

  ltn_stats<<<1024, 256, 0, stream>>>(logits, stats);
  ltn_tile<<<2048, 256, 0, stream>>>(logits, x, stats, wt, xt);
  ltn_gemm_lut<<<1024, 256, 0, stream>>>(xt, wt, lut, out);
}